// Round 1
// 500.175 us; speedup vs baseline: 1.1306x; 1.1306x over previous
//
#include <hip/hip_runtime.h>

#define N_ 2000
#define L_ 1024

__device__ __forceinline__ float rcpf(float d) { return __builtin_amdgcn_rcpf(d); }
__device__ __forceinline__ float ex2(float x)  { return __builtin_amdgcn_exp2f(x); }

// lane <-> lane^1 exchange via DPP quad_perm:[1,0,3,2] -- VALU latency,
// replaces ds_bpermute-based __shfl_xor (DS pipe, ~60-120 cy dependent latency).
__device__ __forceinline__ float dppx1(float x) {
    return __int_as_float(
        __builtin_amdgcn_mov_dpp(__float_as_int(x), 0xB1, 0xF, 0xF, true));
}

// One chain per LANE-PAIR: even lane = M-rates + gates (m,h); odd = N-rates + gates (n,y).
// STEP2: K = timestep (consumes z[K-1], writes out rows K-1,K on store phases),
//        RS = compile-time ring slot = (K-1)&7.
#define STEP2(K, RS, DOSTORE)                                                 \
  {                                                                           \
    const int kk = (K);                                                       \
    float zc = zb[RS];                                                        \
    int kpre = kk + 7;                                                        \
    int kc = kpre < 1998 ? kpre : 1998;                                       \
    zb[RS] = z[base + kc * L_];                                               \
    /* Vn partials: val = m^3*h (even) | n^4 (odd) */                         \
    float w    = evn ? sB : sA;                                               \
    float t1   = sA * sA;                                                     \
    float val  = (t1 * sA) * w;                                               \
    float gAdd = evn ? 0.003f : 0.01f * sB;   /* GL*DT2 | DT2*y */            \
    float Gh   = __fmaf_rn(val, cG, gAdd);                                    \
    float Eh   = __fmaf_rn(val, cE, eAdd);                                    \
    float G    = Gh + dppx1(Gh);                                              \
    float E    = Eh + dppx1(Eh);                                              \
    float num  = __fmaf_rn(V, 1.0f - G, __fmaf_rn(E, 0.02f, 0.02f));          \
    float Vn   = num * rcpf(1.0f + G);                                        \
    /* rates: eR = exp((Vn+35)/9) (even) | exp((Vn-25)/9) (odd), direct */    \
    float eR   = ex2(__fmaf_rn(Vn, K9, cX));                                  \
    float u    = Vn + cu;                                                     \
    float r    = rcpf(eR - 1.0f);                                             \
    float ur   = u * r;                                                       \
    bool  pat  = (Vn == cc);                                                  \
    float av   = pat ? pa  : ka * (ur * eR);                                  \
    float s1   = pat ? cs1 : ur * __fmaf_rn(ka01, eR, kb01);                  \
    /* H-exps: even computes aH, odd computes bH; swap bH to even via DPP */  \
    float vH   = 0.25f * ex2(__fmaf_rn(Vn, sHc, cHc));                        \
    float vHx  = dppx1(vH);                                                   \
    /* gate slot 1: m (even) | n (odd) */                                     \
    float q1   = 1.0f + s1;                                                   \
    float num1 = __fmaf_rn(av, 0.02f, __fmaf_rn(-s1, sA, sA));                \
    /* gate slot 2: h (even) | y (odd) */                                     \
    float a2   = evn ? vH  : zc;                                              \
    float b2   = evn ? vHx : 0.1f;                                            \
    float s2   = __fmaf_rn(a2, 0.01f, 0.01f * b2);                            \
    float q2   = 1.0f + s2;                                                   \
    float num2 = __fmaf_rn(a2, 0.02f, __fmaf_rn(-s2, sB, sB));                \
    float rq   = rcpf(q1 * q2);                                               \
    sA = num1 * (rq * q2);                                                    \
    sB = num2 * (rq * q1);                                                    \
    V = Vn;                                                                   \
    if (DOSTORE) {                                                            \
      /* lanes split output rows K-1 (even, via eRp) and K (odd, via eR) */   \
      /* sigmoid((V+20)/3) = t/(1+t), t = eR^3 * (e^-5 even | e^15 odd) */    \
      float esel = evn ? eRp : eR;                                            \
      float e3 = (esel * esel) * esel;                                        \
      float ts = e3 * C15L;                                                   \
      float sg = ts * rcpf(1.0f + ts);                                        \
      out[base + (kk - 1 + sub) * L_] = sg;                                   \
    } else {                                                                  \
      eRp = eR;                                                               \
    }                                                                         \
  }

__global__ __launch_bounds__(64) void hh_kernel(const float* __restrict__ z,
                                                float* __restrict__ out) {
    const int t   = blockIdx.x * 64 + threadIdx.x;   // 0 .. 32767
    const int sub = t & 1;
    const int ch  = t >> 1;                           // chain 0..16383
    const int b   = ch >> 10;
    const int l   = ch & 1023;
    const int base = b * (N_ * L_) + l;

    const bool evn = (sub == 0);

    const float K9  = 0.16029944898766259f;   // log2(e)/9
    const float K12 = 0.12022458674074695f;   // log2(e)/12

    // per-lane constants (loop-invariant registers)
    const float cG   = evn ? 0.4f      : 0.35f;     // DT2*GNA | DT2*GK
    const float cE   = evn ? 2200.0f   : -2695.0f;  // GNA*ENA | GK*EK
    const float eAdd = evn ? -19.5f    : 0.0f;      // GL*EL   | 0
    const float cu   = evn ? 35.0f     : -25.0f;    // u = Vn + cu
    const float cX   = evn ? 35.0f*K9  : -25.0f*K9; // eR = exp2(Vn*K9 + cX)
    const float cc   = evn ? -35.0f    : 25.0f;     // singularity compare
    const float ka   = evn ? 0.182f    : 0.02f;
    const float ka01 = evn ? 0.00182f  : 0.0002f;   // 0.01*ka
    const float kb01 = evn ? 0.00124f  : 0.00002f;  // 0.01*kb
    const float pa   = evn ? 1.638f    : 0.18f;     // patched a
    const float cs1  = evn ? 0.02798f  : 0.0026f;   // 0.01*(pa+pb)
    const float sHc  = evn ? -K12      : K12;       // argH = sHc*Vn + cHc
    const float cHc  = evn ? -90.0f*K12 : 34.0f*K12;
    const float C15L = evn ? 0.006737946999085467f  // e^-5 (corrects eR_even^3)
                           : 3269017.372472110639f; // e^15

    float V  = -70.0f;
    float sA = 0.0f;                 // m | n
    float sB = evn ? 1.0f : 0.0f;    // h | y
    float eRp = ex2((-70.0f + 35.0f) * K9);   // even-lane eR of initial state

    float zb[8];
#pragma unroll
    for (int i = 0; i < 8; ++i) zb[i] = z[base + i * L_];

    // pair-steps: odd K stores rows (K-1, K); even K saves eRp.
    int k2 = 1;
    for (int g = 0; g < 249; ++g) {          // K = 1 .. 1992
#pragma unroll
        for (int j = 0; j < 4; ++j) {
            STEP2(k2 + 2 * j,     2 * j,     true)
            STEP2(k2 + 2 * j + 1, 2 * j + 1, false)
        }
        k2 += 8;
    }
    // k2 == 1993: remaining pairs K=1993..1998, then K=1999
#pragma unroll
    for (int j = 0; j < 3; ++j) {
        STEP2(k2 + 2 * j,     2 * j,     true)
        STEP2(k2 + 2 * j + 1, 2 * j + 1, false)
    }
    STEP2(1999, 6, true)
}

extern "C" void kernel_launch(void* const* d_in, const int* in_sizes, int n_in,
                              void* d_out, int out_size, void* d_ws, size_t ws_size,
                              hipStream_t stream) {
    const float* z = (const float*)d_in[0];
    float* out = (float*)d_out;
    // 16384 chains x 2 lanes = 32768 threads = 512 waves (2 per CU)
    hh_kernel<<<512, 64, 0, stream>>>(z, out);
}